// Round 1
// baseline (490.372 us; speedup 1.0000x reference)
//
#include <hip/hip_runtime.h>

// Problem constants (reference: B,S,E,H,DK = 2,1024,1024,128,8)
#define Bv  2
#define Sv  1024
#define Ev  1024
#define Hv  128
#define DKv 8
#define Mv  (Bv*Sv)          // 2048 rows in the projection GEMMs

// ---------------------------------------------------------------------------
// GEMM (NT):  C[m,n] = sum_k A[m,k] * W[n,k]  + bias[n]   (+ epilogue)
// A: [M,K] row-major, W: [N,K] row-major (i.e. x @ W.T).
// 64x64 tile, 256 threads, 4x4 micro-tile, BK=16, K-transposed LDS so the
// inner loop is 2x ds_read_b128 + 16 v_fma per kk.
// EPI==0: q-path -> out = cos(acc + bias + phi), written to [B,H,S,DK] layout
// EPI==1: o-path -> out = acc + bias, written to [M,N] (= [B,S,E]) layout
// ---------------------------------------------------------------------------
template<int EPI>
__global__ __launch_bounds__(256)
void gemm_nt(const float* __restrict__ A, const float* __restrict__ W,
             const float* __restrict__ bias, const float* __restrict__ phi,
             float* __restrict__ out, int K)
{
    // pad 64 -> 68 floats: row starts stay 16B-aligned (68*4=272B) for b128
    // reads; transposed scalar writes are <=2-way bank conflicts (free).
    __shared__ float As[16][68];
    __shared__ float Bs[16][68];

    const int t    = threadIdx.x;
    const int tx   = t & 15;          // micro-tile col group
    const int ty   = t >> 4;          // micro-tile row group
    const int tm   = blockIdx.y * 64;
    const int tn   = blockIdx.x * 64;
    const int lrow = t >> 2;          // 0..63  (staging row)
    const int lkq  = t & 3;           // 0..3   (staging k-quad)

    float acc[4][4] = {};

    for (int k0 = 0; k0 < K; k0 += 16) {
        // ---- stage 64x16 A-tile and 64x16 W-tile (one float4 per thread each)
        float4 av = *(const float4*)&A[(size_t)(tm + lrow) * K + k0 + lkq * 4];
        float4 bv = *(const float4*)&W[(size_t)(tn + lrow) * K + k0 + lkq * 4];
        As[lkq*4+0][lrow] = av.x; As[lkq*4+1][lrow] = av.y;
        As[lkq*4+2][lrow] = av.z; As[lkq*4+3][lrow] = av.w;
        Bs[lkq*4+0][lrow] = bv.x; Bs[lkq*4+1][lrow] = bv.y;
        Bs[lkq*4+2][lrow] = bv.z; Bs[lkq*4+3][lrow] = bv.w;
        __syncthreads();

        // ---- compute: 16 kk steps, 2 b128 LDS reads + 16 FMA each
        #pragma unroll
        for (int kk = 0; kk < 16; kk++) {
            float4 a = *(const float4*)&As[kk][ty * 4];
            float4 b = *(const float4*)&Bs[kk][tx * 4];
            float ar[4] = {a.x, a.y, a.z, a.w};
            float br[4] = {b.x, b.y, b.z, b.w};
            #pragma unroll
            for (int i = 0; i < 4; i++)
                #pragma unroll
                for (int j = 0; j < 4; j++)
                    acc[i][j] += ar[i] * br[j];
        }
        __syncthreads();
    }

    // ---- epilogue
    #pragma unroll
    for (int i = 0; i < 4; i++) {
        const int m = tm + ty * 4 + i;
        #pragma unroll
        for (int j = 0; j < 4; j++) {
            const int n = tn + tx * 4 + j;
            if (EPI == 0) {
                // q -> cos(q + phi); scatter to [B,H,S,DK] for attention locality
                float v = __cosf(acc[i][j] + bias[n] + phi[n]);
                const int bb = m >> 10, ss = m & (Sv - 1);   // S = 1024
                const int hh = n >> 3,  dd = n & (DKv - 1);
                out[(((size_t)bb * Hv + hh) * Sv + ss) * DKv + dd] = v;
            } else {
                out[(size_t)m * Ev + n] = acc[i][j] + bias[n];
            }
        }
    }
}

// ---------------------------------------------------------------------------
// Flash-style attention, one (b,h) per blockIdx.x, 256 q-rows per blockIdx.y.
// All S=1024 keys (= values = cos-projected q) staged in LDS (32 KB).
// Each thread owns one q-row: pass1 row-max, pass2 exp-sum + ctx accumulate.
// scores = (out . out)/sqrt(DK); scale folded into the q registers.
// ctx written directly in [B,S,E] layout for the output GEMM.
// ---------------------------------------------------------------------------
__global__ __launch_bounds__(256)
void attn_flash(const float* __restrict__ om, float* __restrict__ ctx)
{
    __shared__ float kb[Sv * DKv];                    // 32 KB
    const int bh = blockIdx.x;                        // 0 .. B*H-1
    const float* base = om + (size_t)bh * Sv * DKv;

    for (int i = threadIdx.x; i < Sv * DKv / 4; i += 256)
        ((float4*)kb)[i] = ((const float4*)base)[i];
    __syncthreads();

    const int qr = blockIdx.y * 256 + threadIdx.x;    // 0..1023
    float q[DKv];
    #pragma unroll
    for (int d = 0; d < DKv; d++)
        q[d] = kb[qr * DKv + d] * 0.35355339059327373f;   // 1/sqrt(8)

    // pass 1: row max (broadcast LDS reads across the wave)
    float mmax = -1e30f;
    for (int tk = 0; tk < Sv; tk++) {
        float s = 0.f;
        #pragma unroll
        for (int d = 0; d < DKv; d++) s += q[d] * kb[tk * DKv + d];
        mmax = fmaxf(mmax, s);
    }

    // pass 2: exp-sum + context accumulation (reuse the loaded key row)
    float l = 0.f, acc[DKv] = {};
    for (int tk = 0; tk < Sv; tk++) {
        float kv[DKv];
        #pragma unroll
        for (int d = 0; d < DKv; d++) kv[d] = kb[tk * DKv + d];
        float s = 0.f;
        #pragma unroll
        for (int d = 0; d < DKv; d++) s += q[d] * kv[d];
        const float p = __expf(s - mmax);
        l += p;
        #pragma unroll
        for (int d = 0; d < DKv; d++) acc[d] += p * kv[d];
    }

    const float inv = 1.0f / l;
    const int bb = bh / Hv, hh = bh % Hv;
    const size_t o = ((size_t)bb * Sv + qr) * Ev + hh * DKv;
    #pragma unroll
    for (int d = 0; d < DKv; d++) ctx[o + d] = acc[d] * inv;
}

// ---------------------------------------------------------------------------
extern "C" void kernel_launch(void* const* d_in, const int* in_sizes, int n_in,
                              void* d_out, int out_size, void* d_ws, size_t ws_size,
                              hipStream_t stream)
{
    const float* x   = (const float*)d_in[0];
    const float* Wq  = (const float*)d_in[1];
    const float* bq  = (const float*)d_in[2];
    // d_in[3..6] = Wk, bk, Wv, bv -- dead in the reference math, skipped.
    const float* phi = (const float*)d_in[7];   // [H,DK] flat == [E]
    const float* Wo  = (const float*)d_in[8];
    const float* bo  = (const float*)d_in[9];
    float* out = (float*)d_out;

    float* om  = (float*)d_ws;                       // [B,H,S,DK]  8.4 MB
    float* ctx = om + (size_t)Bv * Hv * Sv * DKv;    // [B,S,E]     8.4 MB

    const dim3 gg(Ev / 64, Mv / 64);                 // (16, 32)
    gemm_nt<0><<<gg, 256, 0, stream>>>(x, Wq, bq, phi, om, Ev);
    attn_flash<<<dim3(Bv * Hv, Sv / 256), 256, 0, stream>>>(om, ctx);
    gemm_nt<1><<<gg, 256, 0, stream>>>(ctx, Wo, bo, nullptr, out, Ev);
}

// Round 2
// 292.945 us; speedup vs baseline: 1.6739x; 1.6739x over previous
//
#include <hip/hip_runtime.h>
#include <hip/hip_bf16.h>

// Problem constants (reference: B,S,E,H,DK = 2,1024,1024,128,8)
#define Bv  2
#define Sv  1024
#define Ev  1024
#define Hv  128
#define DKv 8
#define Mv  (Bv*Sv)

typedef __attribute__((ext_vector_type(8))) short short8;
typedef __attribute__((ext_vector_type(4))) float f32x4;

static __device__ __forceinline__ short f2b(float f) {
    __hip_bfloat16 h = __float2bfloat16(f);
    return *reinterpret_cast<short*>(&h);
}

// ---------------------------------------------------------------------------
// GEMM (NT):  C[m,n] = sum_k A[m,k] * W[n,k]  + bias[n]   (+ epilogue)
// EPI==0: q-path -> bf16 cos(acc + bias + phi) scattered to [B,H,S,DK]
// EPI==1: o-path -> fp32 acc + bias to [M,N] (= [B,S,E])
// ---------------------------------------------------------------------------
template<int EPI>
__global__ __launch_bounds__(256)
void gemm_nt(const float* __restrict__ A, const float* __restrict__ W,
             const float* __restrict__ bias, const float* __restrict__ phi,
             void* __restrict__ outv, int K)
{
    __shared__ float As[16][68];
    __shared__ float Bs[16][68];

    const int t    = threadIdx.x;
    const int tx   = t & 15;
    const int ty   = t >> 4;
    const int tm   = blockIdx.y * 64;
    const int tn   = blockIdx.x * 64;
    const int lrow = t >> 2;
    const int lkq  = t & 3;

    float acc[4][4] = {};

    for (int k0 = 0; k0 < K; k0 += 16) {
        float4 av = *(const float4*)&A[(size_t)(tm + lrow) * K + k0 + lkq * 4];
        float4 bv = *(const float4*)&W[(size_t)(tn + lrow) * K + k0 + lkq * 4];
        As[lkq*4+0][lrow] = av.x; As[lkq*4+1][lrow] = av.y;
        As[lkq*4+2][lrow] = av.z; As[lkq*4+3][lrow] = av.w;
        Bs[lkq*4+0][lrow] = bv.x; Bs[lkq*4+1][lrow] = bv.y;
        Bs[lkq*4+2][lrow] = bv.z; Bs[lkq*4+3][lrow] = bv.w;
        __syncthreads();

        #pragma unroll
        for (int kk = 0; kk < 16; kk++) {
            float4 a = *(const float4*)&As[kk][ty * 4];
            float4 b = *(const float4*)&Bs[kk][tx * 4];
            float ar[4] = {a.x, a.y, a.z, a.w};
            float br[4] = {b.x, b.y, b.z, b.w};
            #pragma unroll
            for (int i = 0; i < 4; i++)
                #pragma unroll
                for (int j = 0; j < 4; j++)
                    acc[i][j] += ar[i] * br[j];
        }
        __syncthreads();
    }

    #pragma unroll
    for (int i = 0; i < 4; i++) {
        const int m = tm + ty * 4 + i;
        #pragma unroll
        for (int j = 0; j < 4; j++) {
            const int n = tn + tx * 4 + j;
            if (EPI == 0) {
                float v = __cosf(acc[i][j] + bias[n] + phi[n]);
                const int bb = m >> 10, ss = m & (Sv - 1);
                const int hh = n >> 3,  dd = n & (DKv - 1);
                ((short*)outv)[(((size_t)bb * Hv + hh) * Sv + ss) * DKv + dd] = f2b(v);
            } else {
                ((float*)outv)[(size_t)m * Ev + n] = acc[i][j] + bias[n];
            }
        }
    }
}

// ---------------------------------------------------------------------------
// MFMA flash attention. Block = one (b,h) head x 64 q-rows; 4 waves x 16 q.
// No max subtraction needed: |score| <= 8/sqrt(8) = 2.83 -> exp <= 17.
//   scores tile via mfma_f32_16x16x32_bf16 (A=Q 16x32[8 used], B=K^T)
//   p = exp(s/sqrt(8)) in fp32; row-sums kept as per-lane partials
//   P -> bf16 -> per-wave LDS tile -> PV A-frag; V staged transposed in LDS
//   ctx accumulated in ONE mfma C-chain across all 32-key chunks
// ---------------------------------------------------------------------------
__global__ __launch_bounds__(256)
void attn_mfma(const short* __restrict__ om, float* __restrict__ ctx)
{
    __shared__ short K_lds[Sv * DKv];        // [k][d]          16 KB
    __shared__ short Vt[DKv * 1032];         // [d][k] padded   16.5 KB
    __shared__ short P_lds[4 * 16 * 40];     // per-wave [16][40] bf16

    const int t  = threadIdx.x;
    const int bh = blockIdx.x;
    const short* base = om + (size_t)bh * (Sv * DKv);

    // stage keys (rows) + transposed values
    #pragma unroll
    for (int r = 0; r < 4; r++) {
        const int k = r * 256 + t;
        int4 row = ((const int4*)base)[k];
        ((int4*)K_lds)[k] = row;
        union { int4 v; short s[8]; } u; u.v = row;
        #pragma unroll
        for (int d = 0; d < 8; d++) Vt[d * 1032 + k] = u.s[d];
    }
    __syncthreads();

    const int w = t >> 6, lane = t & 63;
    const int c = lane & 15, g = lane >> 4;
    const int q0 = blockIdx.y * 64 + w * 16;
    short* Pw = &P_lds[w * 640];

    // Q fragment (A-layout: row = lane&15, k = 8*(lane>>4)+e; k>=8 zero-padded)
    short8 qf = {};
    if (g == 0) qf = *(const short8*)&K_lds[(q0 + c) * 8];

    f32x4 ctx_acc = {0.f, 0.f, 0.f, 0.f};
    float lsum[4] = {0.f, 0.f, 0.f, 0.f};

    for (int kt = 0; kt < Sv; kt += 32) {
        short8 kf0 = {}, kf1 = {};
        if (g == 0) {
            kf0 = *(const short8*)&K_lds[(kt +      c) * 8];
            kf1 = *(const short8*)&K_lds[(kt + 16 + c) * 8];
        }
        const f32x4 z = {0.f, 0.f, 0.f, 0.f};
        f32x4 s0 = __builtin_amdgcn_mfma_f32_16x16x32_bf16(qf, kf0, z, 0, 0, 0);
        f32x4 s1 = __builtin_amdgcn_mfma_f32_16x16x32_bf16(qf, kf1, z, 0, 0, 0);

        // softmax numerators (D layout: row q = 4g+r, col key = c)
        #pragma unroll
        for (int r = 0; r < 4; r++) {
            float p0 = __expf(s0[r] * 0.35355339f);
            float p1 = __expf(s1[r] * 0.35355339f);
            lsum[r] += p0 + p1;
            Pw[(4 * g + r) * 40 + c]      = f2b(p0);
            Pw[(4 * g + r) * 40 + 16 + c] = f2b(p1);
        }

        // PV: A = P[16q x 32k] from LDS, B = V[32k x 16d] (d>=8 zero)
        short8 pf = *(const short8*)&Pw[c * 40 + 8 * g];
        short8 vf = {};
        if (c < 8) vf = *(const short8*)&Vt[c * 1032 + kt + 8 * g];
        ctx_acc = __builtin_amdgcn_mfma_f32_16x16x32_bf16(pf, vf, ctx_acc, 0, 0, 0);
    }

    // reduce row-sums across the 16-lane col group
    #pragma unroll
    for (int r = 0; r < 4; r++) {
        #pragma unroll
        for (int m = 1; m < 16; m <<= 1)
            lsum[r] += __shfl_xor(lsum[r], m, 16);
    }

    if (c < 8) {
        const int b = bh >> 7, h = bh & (Hv - 1);
        #pragma unroll
        for (int r = 0; r < 4; r++) {
            const int q = q0 + 4 * g + r;
            ctx[((size_t)(b * Sv + q)) * Ev + h * DKv + c] = ctx_acc[r] / lsum[r];
        }
    }
}

// ---------------------------------------------------------------------------
extern "C" void kernel_launch(void* const* d_in, const int* in_sizes, int n_in,
                              void* d_out, int out_size, void* d_ws, size_t ws_size,
                              hipStream_t stream)
{
    const float* x   = (const float*)d_in[0];
    const float* Wq  = (const float*)d_in[1];
    const float* bq  = (const float*)d_in[2];
    // d_in[3..6] = Wk, bk, Wv, bv -- dead in the reference math.
    const float* phi = (const float*)d_in[7];
    const float* Wo  = (const float*)d_in[8];
    const float* bo  = (const float*)d_in[9];
    float* out = (float*)d_out;

    short* om  = (short*)d_ws;                                  // [B,H,S,DK] bf16, 4 MB
    float* ctx = (float*)((char*)d_ws + (size_t)Bv*Hv*Sv*DKv*2); // [B,S,E] fp32, 8.4 MB

    const dim3 gg(Ev / 64, Mv / 64);
    gemm_nt<0><<<gg, 256, 0, stream>>>(x, Wq, bq, phi, (void*)om, Ev);
    attn_mfma<<<dim3(Bv * Hv, Sv / 64), 256, 0, stream>>>(om, ctx);
    gemm_nt<1><<<gg, 256, 0, stream>>>(ctx, Wo, bo, nullptr, (void*)out, Ev);
}

// Round 6
// 184.743 us; speedup vs baseline: 2.6543x; 1.5857x over previous
//
#include <hip/hip_runtime.h>
#include <hip/hip_bf16.h>

// Problem constants (reference: B,S,E,H,DK = 2,1024,1024,128,8)
#define Bv  2
#define Sv  1024
#define Ev  1024
#define Hv  128
#define DKv 8
#define Mv  (Bv*Sv)

typedef __attribute__((ext_vector_type(8))) short short8;
typedef __attribute__((ext_vector_type(4))) float f32x4;

static __device__ __forceinline__ short f2b(float f) {
    __hip_bfloat16 h = __float2bfloat16(f);
    return *reinterpret_cast<short*>(&h);
}

// packed f32x2 -> bf16x2 (low = a, high = b), RNE
static __device__ __forceinline__ unsigned cvtpk(float a, float b) {
    unsigned r;
    asm("v_cvt_pk_bf16_f32 %0, %1, %2" : "=v"(r) : "v"(a), "v"(b));
    return r;
}

// hardware exp2 (v_exp_f32)
static __device__ __forceinline__ float hexp2(float x) {
    return __builtin_amdgcn_exp2f(x);
}

// async global->LDS, 16B per lane; LDS dest = wave-uniform base + lane*16
static __device__ __forceinline__ void gload16(const void* g, void* l) {
    __builtin_amdgcn_global_load_lds(
        (const __attribute__((address_space(1))) unsigned int*)g,
        (__attribute__((address_space(3))) unsigned int*)l, 16, 0, 0);
}

// ---------------------------------------------------------------------------
// fp32 -> bf16 cast kernel (8 elems/thread)
// ---------------------------------------------------------------------------
__global__ __launch_bounds__(256)
void cvt_bf16(const float* __restrict__ in, short* __restrict__ out, int n8)
{
    const int i = blockIdx.x * 256 + threadIdx.x;
    if (i >= n8) return;
    float4 a = ((const float4*)in)[2 * i];
    float4 b = ((const float4*)in)[2 * i + 1];
    uint4 o;
    o.x = cvtpk(a.x, a.y); o.y = cvtpk(a.z, a.w);
    o.z = cvtpk(b.x, b.y); o.w = cvtpk(b.z, b.w);
    ((uint4*)out)[i] = o;
}

// ---------------------------------------------------------------------------
// bf16 MFMA GEMM (NT): C[m,n] = sum_k A[m,k]*W[n,k] (+bias, +epilogue)
// BM=128, BN=64, BK=64. 256 thr = 4 waves (2x2); wave tile 64x32 (4x2 frags).
// Linear LDS + global_load_lds(16B). 2-barrier K-loop (m97 structure).
// EPI==0: om = bf16 cos(acc + bq + phi), scattered to [B,H,S,DK]
// EPI==1: out = fp32 acc + bo, row-major [M,E]
// ---------------------------------------------------------------------------
template<int EPI>
__global__ __launch_bounds__(256)
void gemm_bf16(const short* __restrict__ A, const short* __restrict__ W,
               const float* __restrict__ bias, const float* __restrict__ phi,
               void* __restrict__ outv)
{
    __shared__ short As[128 * 64];   // 16 KB, row-major [128][64]
    __shared__ short Bs[64 * 64];    //  8 KB, row-major [64][64]

    const int t    = threadIdx.x;
    const int w    = t >> 6, lane = t & 63;
    const int c    = lane & 15, g = lane >> 4;
    const int wr   = w >> 1,  wc = w & 1;
    const int tm   = blockIdx.y * 128, tn = blockIdx.x * 64;
    const int lr   = lane >> 3;          // row within 8-row stage group
    const int lc   = (lane & 7) * 8;     // col elems (16B)

    f32x4 acc[4][2] = {};

    for (int k0 = 0; k0 < Ev; k0 += 64) {
        // stage A: wave w covers rows w*32..w*32+31 (4 calls x 8 rows)
        #pragma unroll
        for (int j = 0; j < 4; j++) {
            const int row = w * 32 + j * 8;
            gload16(&A[(size_t)(tm + row + lr) * Ev + k0 + lc], &As[row * 64]);
        }
        // stage B: wave w covers rows w*16..w*16+15 (2 calls x 8 rows)
        #pragma unroll
        for (int j = 0; j < 2; j++) {
            const int row = w * 16 + j * 8;
            gload16(&W[(size_t)(tn + row + lr) * Ev + k0 + lc], &Bs[row * 64]);
        }
        __syncthreads();

        #pragma unroll
        for (int kk = 0; kk < 64; kk += 32) {
            short8 af[4], bf[2];
            #pragma unroll
            for (int m = 0; m < 4; m++)
                af[m] = *(const short8*)&As[(wr * 64 + m * 16 + c) * 64 + kk + 8 * g];
            #pragma unroll
            for (int n = 0; n < 2; n++)
                bf[n] = *(const short8*)&Bs[(wc * 32 + n * 16 + c) * 64 + kk + 8 * g];
            #pragma unroll
            for (int m = 0; m < 4; m++)
                #pragma unroll
                for (int n = 0; n < 2; n++)
                    acc[m][n] = __builtin_amdgcn_mfma_f32_16x16x32_bf16(af[m], bf[n], acc[m][n], 0, 0, 0);
        }
        __syncthreads();
    }

    // epilogue: D layout row = 4*(lane>>4)+reg, col = lane&15
    #pragma unroll
    for (int i = 0; i < 4; i++) {
        #pragma unroll
        for (int j = 0; j < 2; j++) {
            const int n = tn + wc * 32 + j * 16 + c;
            #pragma unroll
            for (int r = 0; r < 4; r++) {
                const int m = tm + wr * 64 + i * 16 + 4 * g + r;
                const float v = acc[i][j][r];
                if (EPI == 0) {
                    float q = __cosf(v + bias[n] + phi[n]);
                    const int bb = m >> 10, ss = m & (Sv - 1);
                    const int hh = n >> 3,  dd = n & (DKv - 1);
                    ((short*)outv)[(((size_t)bb * Hv + hh) * Sv + ss) * DKv + dd] = f2b(q);
                } else {
                    ((float*)outv)[(size_t)m * Ev + n] = v + bias[n];
                }
            }
        }
    }
}

// ---------------------------------------------------------------------------
// MFMA flash attention, swapped-QK^T form. Block = one (b,h) x 64 q-rows,
// 4 waves x 16 q each. No max pass (|score| <= 2.83).
//   S^T tile = mfma(K_frag, Q_frag): D[key=4g+r][q=c]
//   p = exp2(s * 0.5100697) -> packed bf16 pairs -> P[q][k] (b64 writes)
//   PV: A = P row (one b128), B = V^T staged rows; single C-chain accumulate
//   lsum: per-lane partials share one q -> 2 shfl_xor reduce
// ctx written as bf16 [B,S,E] for the MFMA output GEMM.
// ---------------------------------------------------------------------------
__global__ __launch_bounds__(256)
void attn_mfma(const short* __restrict__ om, short* __restrict__ ctx)
{
    __shared__ short K_lds[Sv * DKv];        // [k][d]        16 KB
    __shared__ short Vt[DKv * 1032];         // [d][k] padded 16.5 KB
    __shared__ short P_lds[4][16][40];       // per-wave [q][k] padded, 5 KB

    const int t  = threadIdx.x;
    const int bh = blockIdx.x;
    const short* base = om + (size_t)bh * (Sv * DKv);

    #pragma unroll
    for (int r = 0; r < 4; r++) {
        const int k = r * 256 + t;
        int4 row = ((const int4*)base)[k];
        ((int4*)K_lds)[k] = row;
        union { int4 v; short s[8]; } u; u.v = row;
        #pragma unroll
        for (int d = 0; d < 8; d++) Vt[d * 1032 + k] = u.s[d];
    }
    __syncthreads();

    const int w = t >> 6, lane = t & 63;
    const int c = lane & 15, g = lane >> 4;
    const int q0 = blockIdx.y * 64 + w * 16;

    // Q as B-operand: B[k][q=c] = Q[q][k], k<8 valid (g==0)
    short8 qf = {};
    if (g == 0) qf = *(const short8*)&K_lds[(q0 + c) * 8];

    f32x4 ctx_acc = {0.f, 0.f, 0.f, 0.f};
    float lsum = 0.f;

    for (int kt = 0; kt < Sv; kt += 32) {
        short8 kf0 = {}, kf1 = {};
        if (g == 0) {
            kf0 = *(const short8*)&K_lds[(kt +      c) * 8];
            kf1 = *(const short8*)&K_lds[(kt + 16 + c) * 8];
        }
        const f32x4 z = {0.f, 0.f, 0.f, 0.f};
        f32x4 s0 = __builtin_amdgcn_mfma_f32_16x16x32_bf16(kf0, qf, z, 0, 0, 0);
        f32x4 s1 = __builtin_amdgcn_mfma_f32_16x16x32_bf16(kf1, qf, z, 0, 0, 0);

        // p = exp(s / sqrt(8)) = 2^(s * 0.5100697); all 8 share q = c
        float p[8];
        #pragma unroll
        for (int r = 0; r < 4; r++) {
            p[r]     = hexp2(s0[r] * 0.5100697f);
            p[4 + r] = hexp2(s1[r] * 0.5100697f);
        }
        lsum += ((p[0] + p[1]) + (p[2] + p[3])) + ((p[4] + p[5]) + (p[6] + p[7]));

        // P[q=c][key]: s0 -> keys 4g..4g+3, s1 -> keys 16+4g..16+4g+3
        uint2 w0, w1;
        w0.x = cvtpk(p[0], p[1]); w0.y = cvtpk(p[2], p[3]);
        w1.x = cvtpk(p[4], p[5]); w1.y = cvtpk(p[6], p[7]);
        *(uint2*)&P_lds[w][c][4 * g]      = w0;
        *(uint2*)&P_lds[w][c][16 + 4 * g] = w1;

        // PV: A = P[q=c][8g..8g+7] (b128), B = V[k][d] via Vt rows
        short8 pf = *(const short8*)&P_lds[w][c][8 * g];
        short8 vf = {};
        if (c < 8) vf = *(const short8*)&Vt[c * 1032 + kt + 8 * g];
        ctx_acc = __builtin_amdgcn_mfma_f32_16x16x32_bf16(pf, vf, ctx_acc, 0, 0, 0);
    }

    // reduce lsum across lanes sharing q (=c): lanes c, c+16, c+32, c+48
    lsum += __shfl_xor(lsum, 16);
    lsum += __shfl_xor(lsum, 32);
    // lane needs L for its output rows q = 4g+r (all lanes active for shfl)
    float L[4];
    #pragma unroll
    for (int r = 0; r < 4; r++) L[r] = __shfl(lsum, 4 * g + r);

    if (c < 8) {
        const int b = bh >> 7, h = bh & (Hv - 1);
        #pragma unroll
        for (int r = 0; r < 4; r++) {
            const int q = q0 + 4 * g + r;
            ctx[((size_t)(b * Sv + q)) * Ev + h * DKv + c] = f2b(ctx_acc[r] / L[r]);
        }
    }
}

// ---------------------------------------------------------------------------
extern "C" void kernel_launch(void* const* d_in, const int* in_sizes, int n_in,
                              void* d_out, int out_size, void* d_ws, size_t ws_size,
                              hipStream_t stream)
{
    const float* x   = (const float*)d_in[0];
    const float* Wq  = (const float*)d_in[1];
    const float* bq  = (const float*)d_in[2];
    // d_in[3..6] = Wk, bk, Wv, bv -- dead in the reference math.
    const float* phi = (const float*)d_in[7];
    const float* Wo  = (const float*)d_in[8];
    const float* bo  = (const float*)d_in[9];
    float* out = (float*)d_out;

    char* ws = (char*)d_ws;
    short* xb  = (short*)ws;                       // [M,E] bf16, 4 MB
    short* ctx = xb;                               // alias: ctx written after xb's last read
    short* om  = (short*)(ws + (4 << 20));         // [B,H,S,DK] bf16, 4 MB
    short* Wqb = (short*)(ws + (8 << 20));         // [E,E] bf16, 2 MB
    short* Wob = (short*)(ws + (10 << 20));        // [E,E] bf16, 2 MB

    cvt_bf16<<<dim3(Mv * Ev / 2048), 256, 0, stream>>>(x,  xb,  Mv * Ev / 8);
    cvt_bf16<<<dim3(Ev * Ev / 2048), 256, 0, stream>>>(Wq, Wqb, Ev * Ev / 8);
    cvt_bf16<<<dim3(Ev * Ev / 2048), 256, 0, stream>>>(Wo, Wob, Ev * Ev / 8);

    const dim3 gg(Ev / 64, Mv / 128);              // (16, 16) = 256 blocks
    gemm_bf16<0><<<gg, 256, 0, stream>>>(xb, Wqb, bq, phi, (void*)om);
    attn_mfma<<<dim3(Bv * Hv, Sv / 64), 256, 0, stream>>>(om, ctx);
    gemm_bf16<1><<<gg, 256, 0, stream>>>(ctx, Wob, bo, nullptr, (void*)out);
}

// Round 8
// 174.146 us; speedup vs baseline: 2.8159x; 1.0609x over previous
//
#include <hip/hip_runtime.h>
#include <hip/hip_bf16.h>

// Problem constants (reference: B,S,E,H,DK = 2,1024,1024,128,8)
#define Bv  2
#define Sv  1024
#define Ev  1024
#define Hv  128
#define DKv 8
#define Mv  (Bv*Sv)

typedef __attribute__((ext_vector_type(8))) short short8;
typedef __attribute__((ext_vector_type(4))) float f32x4;

static __device__ __forceinline__ short f2b(float f) {
    __hip_bfloat16 h = __float2bfloat16(f);
    return *reinterpret_cast<short*>(&h);
}

// packed f32x2 -> bf16x2 (low = a, high = b), RNE
static __device__ __forceinline__ unsigned cvtpk(float a, float b) {
    unsigned r;
    asm("v_cvt_pk_bf16_f32 %0, %1, %2" : "=v"(r) : "v"(a), "v"(b));
    return r;
}

// hardware exp2 (v_exp_f32)
static __device__ __forceinline__ float hexp2(float x) {
    return __builtin_amdgcn_exp2f(x);
}

// async global->LDS, 16B per lane; LDS dest = wave-uniform base + lane*16
static __device__ __forceinline__ void gload16(const void* g, void* l) {
    __builtin_amdgcn_global_load_lds(
        (const __attribute__((address_space(1))) unsigned int*)g,
        (__attribute__((address_space(3))) unsigned int*)l, 16, 0, 0);
}

// ---------------------------------------------------------------------------
// fused fp32 -> bf16 cast for x (1024 blk), Wq (512 blk), Wo (512 blk)
// ---------------------------------------------------------------------------
__global__ __launch_bounds__(256)
void cvt_all(const float* __restrict__ x, const float* __restrict__ wq,
             const float* __restrict__ wo, short* __restrict__ xb,
             short* __restrict__ wqb, short* __restrict__ wob)
{
    const int b = blockIdx.x;
    const float* src; short* dst; int i;
    if (b < 1024)      { src = x;  dst = xb;  i = b * 256 + threadIdx.x; }
    else if (b < 1536) { src = wq; dst = wqb; i = (b - 1024) * 256 + threadIdx.x; }
    else               { src = wo; dst = wob; i = (b - 1536) * 256 + threadIdx.x; }
    float4 a = ((const float4*)src)[2 * i];
    float4 c = ((const float4*)src)[2 * i + 1];
    uint4 o;
    o.x = cvtpk(a.x, a.y); o.y = cvtpk(a.z, a.w);
    o.z = cvtpk(c.x, c.y); o.w = cvtpk(c.z, c.w);
    ((uint4*)dst)[i] = o;
}

// ---------------------------------------------------------------------------
// bf16 MFMA GEMM (NT): C[m,n] = sum_k A[m,k]*W[n,k] (+bias, +epilogue)
// BM=BN=64, BK=64 -> grid (16,32)=512 blocks (2/CU). 4 waves (2x2), wave
// tile 32x32 (2x2 16x16 frags). LDS double-buffered; next K-tile staged via
// global_load_lds before computing current; one barrier per K-step.
// XOR-swizzled LDS (rule 21: swizzle the GLOBAL source slot, read with
// slot ^ (row&7)) -> conflict-free ds_read_b128.
// EPI==0: om = bf16 cos(acc + bq + phi), scattered to [B,H,S,DK]
// EPI==1: out = fp32 acc + bo, row-major [M,E]
// ---------------------------------------------------------------------------
template<int EPI>
__global__ __launch_bounds__(256)
void gemm_bf16(const short* __restrict__ A, const short* __restrict__ W,
               const float* __restrict__ bias, const float* __restrict__ phi,
               void* __restrict__ outv)
{
    __shared__ short As[2][64 * 64];   // 8 KB each
    __shared__ short Bs[2][64 * 64];

    const int t    = threadIdx.x;
    const int w    = t >> 6, lane = t & 63;
    const int c    = lane & 15, g = lane >> 4;
    const int cs   = c & 7;
    const int wr   = w >> 1,  wc = w & 1;
    const int tm   = blockIdx.y * 64, tn = blockIdx.x * 64;
    const int lr   = lane >> 3;                    // 0..7: row in 8-row group
    const int lcs  = ((lane & 7) ^ lr) * 8;        // swizzled source col slot

    f32x4 acc[2][2] = {};

    // stage K-step k0 into buffer s (wave w: rows w*16 .. w*16+15 of both tiles)
    #define STAGE(s, k0)                                                        \
        _Pragma("unroll")                                                       \
        for (int j = 0; j < 2; j++) {                                           \
            const int row = w * 16 + j * 8;                                     \
            gload16(&A[(size_t)(tm + row + lr) * Ev + (k0) + lcs], &As[s][row * 64]); \
            gload16(&W[(size_t)(tn + row + lr) * Ev + (k0) + lcs], &Bs[s][row * 64]); \
        }

    STAGE(0, 0)
    __syncthreads();

    for (int ks = 0; ks < 16; ks++) {
        const int cur = ks & 1;
        if (ks < 15) { STAGE(cur ^ 1, (ks + 1) * 64) }
        #pragma unroll
        for (int kk = 0; kk < 64; kk += 32) {
            const int s0 = ((kk >> 3) + g) ^ cs;   // swizzled read slot
            short8 af[2], bf[2];
            #pragma unroll
            for (int m = 0; m < 2; m++)
                af[m] = *(const short8*)&As[cur][(wr * 32 + m * 16 + c) * 64 + s0 * 8];
            #pragma unroll
            for (int n = 0; n < 2; n++)
                bf[n] = *(const short8*)&Bs[cur][(wc * 32 + n * 16 + c) * 64 + s0 * 8];
            #pragma unroll
            for (int m = 0; m < 2; m++)
                #pragma unroll
                for (int n = 0; n < 2; n++)
                    acc[m][n] = __builtin_amdgcn_mfma_f32_16x16x32_bf16(af[m], bf[n], acc[m][n], 0, 0, 0);
        }
        __syncthreads();
    }

    // epilogue: D layout row = 4*(lane>>4)+reg, col = lane&15
    #pragma unroll
    for (int i = 0; i < 2; i++) {
        #pragma unroll
        for (int j = 0; j < 2; j++) {
            const int n = tn + wc * 32 + j * 16 + c;
            #pragma unroll
            for (int r = 0; r < 4; r++) {
                const int m = tm + wr * 32 + i * 16 + 4 * g + r;
                const float v = acc[i][j][r];
                if (EPI == 0) {
                    float q = __cosf(v + bias[n] + phi[n]);
                    const int bb = m >> 10, ss = m & (Sv - 1);
                    const int hh = n >> 3,  dd = n & (DKv - 1);
                    ((short*)outv)[(((size_t)bb * Hv + hh) * Sv + ss) * DKv + dd] = f2b(q);
                } else {
                    ((float*)outv)[(size_t)m * Ev + n] = v + bias[n];
                }
            }
        }
    }
    #undef STAGE
}

// ---------------------------------------------------------------------------
// MFMA flash attention (round-6 verbatim, known good). Swapped-QK^T form.
// Block = one (b,h) x 64 q-rows, 4 waves x 16 q each. No max pass.
// ---------------------------------------------------------------------------
__global__ __launch_bounds__(256)
void attn_mfma(const short* __restrict__ om, short* __restrict__ ctx)
{
    __shared__ short K_lds[Sv * DKv];        // [k][d]        16 KB
    __shared__ short Vt[DKv * 1032];         // [d][k] padded 16.5 KB
    __shared__ short P_lds[4][16][40];       // per-wave [q][k] padded, 5 KB

    const int t  = threadIdx.x;
    const int bh = blockIdx.x;
    const short* base = om + (size_t)bh * (Sv * DKv);

    #pragma unroll
    for (int r = 0; r < 4; r++) {
        const int k = r * 256 + t;
        int4 row = ((const int4*)base)[k];
        ((int4*)K_lds)[k] = row;
        union { int4 v; short s[8]; } u; u.v = row;
        #pragma unroll
        for (int d = 0; d < 8; d++) Vt[d * 1032 + k] = u.s[d];
    }
    __syncthreads();

    const int w = t >> 6, lane = t & 63;
    const int c = lane & 15, g = lane >> 4;
    const int q0 = blockIdx.y * 64 + w * 16;

    // Q as B-operand: B[k][q=c] = Q[q][k], k<8 valid (g==0 lanes)
    short8 qf = {};
    if (g == 0) qf = *(const short8*)&K_lds[(q0 + c) * 8];

    f32x4 ctx_acc = {0.f, 0.f, 0.f, 0.f};
    float lsum = 0.f;

    for (int kt = 0; kt < Sv; kt += 32) {
        short8 kf0 = {}, kf1 = {};
        if (g == 0) {
            kf0 = *(const short8*)&K_lds[(kt +      c) * 8];
            kf1 = *(const short8*)&K_lds[(kt + 16 + c) * 8];
        }
        const f32x4 z = {0.f, 0.f, 0.f, 0.f};
        f32x4 s0 = __builtin_amdgcn_mfma_f32_16x16x32_bf16(kf0, qf, z, 0, 0, 0);
        f32x4 s1 = __builtin_amdgcn_mfma_f32_16x16x32_bf16(kf1, qf, z, 0, 0, 0);

        // p = exp(s / sqrt(8)) = 2^(s * 0.5100697); all 8 share q = c
        float p[8];
        #pragma unroll
        for (int r = 0; r < 4; r++) {
            p[r]     = hexp2(s0[r] * 0.5100697f);
            p[4 + r] = hexp2(s1[r] * 0.5100697f);
        }
        lsum += ((p[0] + p[1]) + (p[2] + p[3])) + ((p[4] + p[5]) + (p[6] + p[7]));

        // P[q=c][key]: s0 -> keys 4g..4g+3, s1 -> keys 16+4g..16+4g+3
        uint2 w0, w1;
        w0.x = cvtpk(p[0], p[1]); w0.y = cvtpk(p[2], p[3]);
        w1.x = cvtpk(p[4], p[5]); w1.y = cvtpk(p[6], p[7]);
        *(uint2*)&P_lds[w][c][4 * g]      = w0;
        *(uint2*)&P_lds[w][c][16 + 4 * g] = w1;

        // PV: A = P[q=c][8g..8g+7] (b128), B = V[k][d] via Vt rows
        short8 pf = *(const short8*)&P_lds[w][c][8 * g];
        short8 vf = {};
        if (c < 8) vf = *(const short8*)&Vt[c * 1032 + kt + 8 * g];
        ctx_acc = __builtin_amdgcn_mfma_f32_16x16x32_bf16(pf, vf, ctx_acc, 0, 0, 0);
    }

    // reduce lsum across lanes sharing q (=c): lanes c, c+16, c+32, c+48
    lsum += __shfl_xor(lsum, 16);
    lsum += __shfl_xor(lsum, 32);
    // lane needs L for its output rows q = 4g+r (all lanes active for shfl)
    float L[4];
    #pragma unroll
    for (int r = 0; r < 4; r++) L[r] = __shfl(lsum, 4 * g + r);

    if (c < 8) {
        const int b = bh >> 7, h = bh & (Hv - 1);
        #pragma unroll
        for (int r = 0; r < 4; r++) {
            const int q = q0 + 4 * g + r;
            ctx[((size_t)(b * Sv + q)) * Ev + h * DKv + c] = f2b(ctx_acc[r] / L[r]);
        }
    }
}

// ---------------------------------------------------------------------------
extern "C" void kernel_launch(void* const* d_in, const int* in_sizes, int n_in,
                              void* d_out, int out_size, void* d_ws, size_t ws_size,
                              hipStream_t stream)
{
    const float* x   = (const float*)d_in[0];
    const float* Wq  = (const float*)d_in[1];
    const float* bq  = (const float*)d_in[2];
    // d_in[3..6] = Wk, bk, Wv, bv -- dead in the reference math.
    const float* phi = (const float*)d_in[7];
    const float* Wo  = (const float*)d_in[8];
    const float* bo  = (const float*)d_in[9];
    float* out = (float*)d_out;

    char* ws = (char*)d_ws;
    short* xb  = (short*)ws;                       // [M,E] bf16, 4 MB
    short* ctx = xb;                               // alias: written after xb's last read
    short* om  = (short*)(ws + (4 << 20));         // [B,H,S,DK] bf16, 4 MB
    short* Wqb = (short*)(ws + (8 << 20));         // [E,E] bf16, 2 MB
    short* Wob = (short*)(ws + (10 << 20));        // [E,E] bf16, 2 MB

    cvt_all<<<dim3(2048), 256, 0, stream>>>(x, Wq, Wo, xb, Wqb, Wob);

    const dim3 gg(Ev / 64, Mv / 64);               // (16, 32) = 512 blocks
    gemm_bf16<0><<<gg, 256, 0, stream>>>(xb, Wqb, bq, phi, (void*)om);
    attn_mfma<<<dim3(Bv * Hv, Sv / 64), 256, 0, stream>>>(om, ctx);
    gemm_bf16<1><<<gg, 256, 0, stream>>>(ctx, Wob, bo, nullptr, (void*)out);
}